// Round 9
// baseline (164.315 us; speedup 1.0000x reference)
//
#include <hip/hip_runtime.h>

#define BB 32
#define VV 48
#define CC 24
#define AA 6
#define NCODES 10001
#define DD 128
#define HH 128
#define OUTN 167
#define G3 384  // 3*H

typedef float f32x4 __attribute__((ext_vector_type(4)));

__device__ __forceinline__ float fast_tanh(float x) {
    return 1.0f - 2.0f / (1.0f + __expf(2.0f * x));
}
__device__ __forceinline__ float fast_sigmoid(float x) {
    return 1.0f / (1.0f + __expf(-x));
}
__device__ __forceinline__ float dot4(float4 a, float4 b) {
    return a.x * b.x + a.y * b.y + a.z * b.z + a.w * b.w;
}
__device__ __forceinline__ float dot4v(f32x4 a, f32x4 b) {
    return a.x * b.x + a.y * b.y + a.z * b.z + a.w * b.w;
}

// K1: P1[c,e] = sum_d emb[c,d]*W[e,d]; P2[c,e] = sum_d emb[c,d]*W[e,128+d]
// NO LDS: emb rows are read at wave-uniform addresses (1 transaction, 8KB
// L1-resident working set) -- removes the 4096 ds_read_b32/block issue cost
// that made the LDS version LDS-unit-bound. 2 output cols per thread (P1+P2
// share the same w row) -> 8 FMA per emb load. acc[2][8]=16 regs, no arrays
// big enough to spill (rounds 2/4/5/6 lesson).
__global__ __launch_bounds__(256) void k_precompute(
    const float* __restrict__ emb, const float* __restrict__ w_basic,
    float* __restrict__ P1, float* __restrict__ P2, int nrows)
{
    int row0 = blockIdx.x * 16;
    int t = threadIdx.x;
    int tc = t & 127, grp = t >> 7;
    int rbase = row0 + grp * 8;
    const float4* w4 = (const float4*)w_basic;   // [128 rows][64 float4]
    const float4* e4 = (const float4*)emb;       // [nrows][32 float4]
    float a0[8] = {}, a1[8] = {};
#pragma unroll 2
    for (int d4 = 0; d4 < 32; ++d4) {
        float4 wv0 = w4[tc * 64 + d4];        // w_basic[tc][d4*4 ..]      (P1 half)
        float4 wv1 = w4[tc * 64 + 32 + d4];   // w_basic[tc][128 + d4*4..] (P2 half)
#pragma unroll
        for (int r = 0; r < 8; ++r) {
            int row = rbase + r;
            if (row >= nrows) row = nrows - 1;   // clamp; store is guarded
            float4 ev = e4[row * 32 + d4];       // wave-uniform address
            a0[r] += dot4(ev, wv0);
            a1[r] += dot4(ev, wv1);
        }
    }
#pragma unroll
    for (int r = 0; r < 8; ++r) {
        int row = rbase + r;
        if (row < nrows) {
            P1[row * 128 + tc] = a0[r];
            P2[row * 128 + tc] = a1[r];
        }
    }
}

// K2: attention + visit embedding x[bv,128]  (unchanged)
__global__ __launch_bounds__(256) void k_attention(
    const int* __restrict__ seqs, const int* __restrict__ ancestors,
    const float* __restrict__ amask, const float* __restrict__ emb,
    const float* __restrict__ P1, const float* __restrict__ P2,
    const float* __restrict__ u_w, const float* __restrict__ u_b,
    float* __restrict__ x_out)
{
    __shared__ __align__(16) float u_s[128];
    __shared__ float sc_s[144];
    __shared__ float m_s[144];
    __shared__ int   anc_s[144];
    __shared__ float attn_s[144];
    __shared__ float sum_s[24];
    __shared__ float xred[256];
    int bv = blockIdx.x;
    int t = threadIdx.x;
    if (t < 128) u_s[t] = u_w[t];
    __syncthreads();
    float ub = u_b[0];
    int g = t >> 2, l = t & 3;
    for (int p = g; p < CC * AA; p += 64) {
        int c = p / AA, a = p - c * AA;
        int sidx = bv * CC + c;
        int s_code = seqs[sidx];
        int aidx = sidx * AA + a;
        int anc = ancestors[aidx];
        float m = amask[aidx];
        const float4* p14 = (const float4*)(P1 + s_code * 128);
        const float4* p24 = (const float4*)(P2 + anc * 128);
        const float4* u4 = (const float4*)u_s;
        float partial = 0.0f;
        int e4 = l * 8;
#pragma unroll 2
        for (int j = 0; j < 8; ++j) {
            float4 av = p14[e4 + j];
            float4 bv_ = p24[e4 + j];
            float4 uv = u4[e4 + j];
            partial += fast_tanh(m * (av.x + bv_.x)) * uv.x;
            partial += fast_tanh(m * (av.y + bv_.y)) * uv.y;
            partial += fast_tanh(m * (av.z + bv_.z)) * uv.z;
            partial += fast_tanh(m * (av.w + bv_.w)) * uv.w;
        }
        partial += __shfl_xor(partial, 1);
        partial += __shfl_xor(partial, 2);
        if (l == 0) {
            sc_s[p] = partial + ub;
            m_s[p] = m;
            anc_s[p] = anc;
        }
    }
    __syncthreads();
    if (t < CC * AA) attn_s[t] = __expf(sc_s[t]) * m_s[t];
    __syncthreads();
    if (t < CC) {
        float s = 0.0f;
#pragma unroll
        for (int a = 0; a < AA; ++a) s += attn_s[t * AA + a];
        sum_s[t] = (s == 0.0f) ? -1.0f : s;
    }
    __syncthreads();
    if (t < CC * AA) attn_s[t] = attn_s[t] / sum_s[t / AA];
    __syncthreads();
    int e = t & 127, hc = t >> 7;
    float acc = 0.0f;
    for (int c = hc * 12; c < hc * 12 + 12; ++c) {
#pragma unroll
        for (int a = 0; a < AA; ++a) {
            int p = c * AA + a;
            acc += attn_s[p] * emb[anc_s[p] * 128 + e];
        }
    }
    xred[t] = acc;
    __syncthreads();
    if (t < 128) {
        x_out[bv * 128 + t] = fast_tanh(xred[t] + xred[t + 128]);
    }
}

// K3: gi[bv,o] = sum_d x[bv,d]*Wih[o,d] + bih[o]
// Same no-LDS treatment: x rows at block-uniform addresses.
__global__ __launch_bounds__(384) void k_gi(
    const float* __restrict__ x, const float* __restrict__ wih,
    const float* __restrict__ bih, float* __restrict__ gi)
{
    int row0 = blockIdx.x * 8;
    int t = threadIdx.x;
    const float4* w4 = (const float4*)(wih + t * 128);
    const float4* x4 = (const float4*)(x + row0 * 128);
    float acc[8] = {};
#pragma unroll 2
    for (int d4 = 0; d4 < 32; ++d4) {
        float4 wv = w4[d4];
#pragma unroll
        for (int r = 0; r < 8; ++r) {
            acc[r] += dot4(x4[r * 32 + d4], wv);
        }
    }
    float bb = bih[t];
#pragma unroll
    for (int r = 0; r < 8; ++r) gi[(row0 + r) * G3 + t] = acc[r] + bb;
}

// Volatile asm load: cannot be sunk/re-executed; weights stay on-chip.
#define GL4(dst, base, OFF) \
    asm volatile("global_load_dwordx4 %0, %1, off offset:" #OFF \
                 : "=v"(dst) : "v"(base))

// K4: sequential GRU. Round-9 change: ZERO in-loop global loads.
// hipcc drains vmcnt(0) before every s_barrier (guide §5) -- the old per-step
// gi prefetch therefore exposed a full L3/HBM latency at EVERY barrier
// (the ~2700 cyc/step mystery, invariant across rounds 1-8). gi is now staged
// into LDS in two 24-step phases: exactly 2 vmem drains for the whole loop.
__global__ __launch_bounds__(256, 1) void k_gru(
    const float* __restrict__ gi, const float* __restrict__ whh,
    const float* __restrict__ bhh, const int* __restrict__ length,
    const float* __restrict__ out_w, const float* __restrict__ out_b,
    float* __restrict__ out)
{
    __shared__ __align__(16) float gl[24 * G3];      // 36,864 B
    __shared__ __align__(16) float hs[2][128];
    __shared__ __align__(16) float ctxs[128];
    int b = blockIdx.x;
    int t = threadIdx.x;
    int o = t >> 1, half = t & 1;

    const f32x4* bwr = (const f32x4*)(whh + o * 128 + half * 64);
    const f32x4* bwz = (const f32x4*)(whh + (128 + o) * 128 + half * 64);
    const f32x4* bwn = (const f32x4*)(whh + (256 + o) * 128 + half * 64);

    f32x4 wr0, wr1, wr2, wr3, wr4, wr5, wr6, wr7,
          wr8, wr9, wr10, wr11, wr12, wr13, wr14, wr15;
    f32x4 wz0, wz1, wz2, wz3, wz4, wz5, wz6, wz7,
          wz8, wz9, wz10, wz11, wz12, wz13, wz14, wz15;
    f32x4 wn0, wn1, wn2, wn3, wn4, wn5, wn6, wn7,
          wn8, wn9, wn10, wn11, wn12, wn13, wn14, wn15;

    GL4(wr0,  bwr, 0);   GL4(wr1,  bwr, 16);  GL4(wr2,  bwr, 32);  GL4(wr3,  bwr, 48);
    GL4(wr4,  bwr, 64);  GL4(wr5,  bwr, 80);  GL4(wr6,  bwr, 96);  GL4(wr7,  bwr, 112);
    GL4(wr8,  bwr, 128); GL4(wr9,  bwr, 144); GL4(wr10, bwr, 160); GL4(wr11, bwr, 176);
    GL4(wr12, bwr, 192); GL4(wr13, bwr, 208); GL4(wr14, bwr, 224); GL4(wr15, bwr, 240);
    GL4(wz0,  bwz, 0);   GL4(wz1,  bwz, 16);  GL4(wz2,  bwz, 32);  GL4(wz3,  bwz, 48);
    GL4(wz4,  bwz, 64);  GL4(wz5,  bwz, 80);  GL4(wz6,  bwz, 96);  GL4(wz7,  bwz, 112);
    GL4(wz8,  bwz, 128); GL4(wz9,  bwz, 144); GL4(wz10, bwz, 160); GL4(wz11, bwz, 176);
    GL4(wz12, bwz, 192); GL4(wz13, bwz, 208); GL4(wz14, bwz, 224); GL4(wz15, bwz, 240);
    GL4(wn0,  bwn, 0);   GL4(wn1,  bwn, 16);  GL4(wn2,  bwn, 32);  GL4(wn3,  bwn, 48);
    GL4(wn4,  bwn, 64);  GL4(wn5,  bwn, 80);  GL4(wn6,  bwn, 96);  GL4(wn7,  bwn, 112);
    GL4(wn8,  bwn, 128); GL4(wn9,  bwn, 144); GL4(wn10, bwn, 160); GL4(wn11, bwn, 176);
    GL4(wn12, bwn, 192); GL4(wn13, bwn, 208); GL4(wn14, bwn, 224); GL4(wn15, bwn, 240);

    const float4* gib4 = (const float4*)(gi + b * VV * G3);
    // stage phase 0: steps [0,24) -> 2304 float4, 9 per thread (coalesced)
    {
        float4* dst = (float4*)gl;
#pragma unroll
        for (int i = 0; i < 9; ++i) dst[t + i * 256] = gib4[t + i * 256];
    }

    float bhr = 0.f, bhz = 0.f, bhn = 0.f;
    if (half == 0) {
        bhr = bhh[o];
        bhz = bhh[128 + o];
        bhn = bhh[256 + o];
    }
    if (t < 128) hs[0][t] = 0.0f;
    int len = length[b];
    float ctx = 0.0f;

    // drain weight asm loads + staging loads once; fence first use (rule #18)
    asm volatile("s_waitcnt vmcnt(0)" ::: "memory");
    __builtin_amdgcn_sched_barrier(0);
    __syncthreads();

#define STEP2(J, A, B_) do {                                          \
        f32x4 hA = h4[J]; f32x4 hB = h4[J + 1];                       \
        ar0 += dot4v(wr##A, hA);  ar1 += dot4v(wr##B_, hB);           \
        az0 += dot4v(wz##A, hA);  az1 += dot4v(wz##B_, hB);           \
        an0 += dot4v(wn##A, hA);  an1 += dot4v(wn##B_, hB);           \
    } while (0)

    int cur = 0;
    for (int v = 0; v < VV; ++v) {
        if (v == 24) {
            // loop-end barrier of step 23 already passed: safe to overwrite
            float4* dst = (float4*)gl;
            const float4* src = gib4 + 2304;
#pragma unroll
            for (int i = 0; i < 9; ++i) dst[t + i * 256] = src[t + i * 256];
            __syncthreads();   // one drain for phase 1
        }
        int vv = (v >= 24) ? (v - 24) : v;
        float gir = 0.f, giz = 0.f, gin = 0.f;
        if (half == 0) {
            const float* g = gl + vv * G3;
            gir = g[o]; giz = g[128 + o]; gin = g[256 + o];
        }
        const f32x4* h4 = ((const f32x4*)hs[cur]) + half * 16;
        float ar0 = 0.f, ar1 = 0.f, az0 = 0.f, az1 = 0.f, an0 = 0.f, an1 = 0.f;
        STEP2(0, 0, 1);   STEP2(2, 2, 3);    STEP2(4, 4, 5);    STEP2(6, 6, 7);
        STEP2(8, 8, 9);   STEP2(10, 10, 11); STEP2(12, 12, 13); STEP2(14, 14, 15);
        float ar = ar0 + ar1;
        float az = az0 + az1;
        float an = an0 + an1;
        ar += __shfl_xor(ar, 1);
        az += __shfl_xor(az, 1);
        an += __shfl_xor(an, 1);
        if (half == 0) {
            float r = fast_sigmoid(gir + ar + bhr);
            float z = fast_sigmoid(giz + az + bhz);
            float n = fast_tanh(gin + r * (an + bhn));
            float hold = hs[cur][o];
            float hnew = (1.0f - z) * n + z * hold;
            hs[cur ^ 1][o] = hnew;
            if (v < len) ctx += hnew;
        }
        cur ^= 1;
        __syncthreads();
    }
#undef STEP2

    if (half == 0) ctxs[o] = ctx;
    __syncthreads();
    if (t < OUTN) {
        const float4* w4 = (const float4*)(out_w + t * 128);
        const float4* c4 = (const float4*)ctxs;
        float a0 = 0.f, a1 = 0.f;
#pragma unroll 2
        for (int j = 0; j < 32; j += 2) {
            a0 += dot4(w4[j], c4[j]);
            a1 += dot4(w4[j + 1], c4[j + 1]);
        }
        out[b * OUTN + t] = fast_sigmoid(a0 + a1 + out_b[t]);
    }
}

extern "C" void kernel_launch(void* const* d_in, const int* in_sizes, int n_in,
                              void* d_out, int out_size, void* d_ws, size_t ws_size,
                              hipStream_t stream) {
    const int*   seqs      = (const int*)d_in[0];
    const int*   ancestors = (const int*)d_in[1];
    const int*   length    = (const int*)d_in[2];
    const float* amask     = (const float*)d_in[3];
    const float* emb       = (const float*)d_in[4];
    const float* w_basic   = (const float*)d_in[5];
    const float* u_w       = (const float*)d_in[6];
    const float* u_b       = (const float*)d_in[7];
    const float* wih       = (const float*)d_in[8];
    const float* whh       = (const float*)d_in[9];
    const float* bih       = (const float*)d_in[10];
    const float* bhh       = (const float*)d_in[11];
    const float* out_w     = (const float*)d_in[12];
    const float* out_b     = (const float*)d_in[13];
    float* out = (float*)d_out;

    float* ws = (float*)d_ws;
    float* P1 = ws;                       // [10001,128]
    float* P2 = P1 + NCODES * 128;        // [10001,128]
    float* x  = P2 + NCODES * 128;        // [1536,128]
    float* gi = x + BB * VV * 128;        // [1536,384]

    k_precompute<<<(NCODES + 15) / 16, 256, 0, stream>>>(emb, w_basic, P1, P2, NCODES);
    k_attention<<<BB * VV, 256, 0, stream>>>(seqs, ancestors, amask, emb, P1, P2, u_w, u_b, x);
    k_gi<<<(BB * VV) / 8, 384, 0, stream>>>(x, wih, bih, gi);
    k_gru<<<BB, 256, 0, stream>>>(gi, whh, bhh, length, out_w, out_b, out);
}

// Round 10
// 153.665 us; speedup vs baseline: 1.0693x; 1.0693x over previous
//
#include <hip/hip_runtime.h>

#define BB 32
#define VV 48
#define CC 24
#define AA 6
#define NCODES 10001
#define DD 128
#define HH 128
#define OUTN 167
#define G3 384  // 3*H

typedef float f32x4 __attribute__((ext_vector_type(4)));

__device__ __forceinline__ float fast_tanh(float x) {
    return 1.0f - 2.0f / (1.0f + __expf(2.0f * x));
}
__device__ __forceinline__ float fast_sigmoid(float x) {
    return 1.0f / (1.0f + __expf(-x));
}
__device__ __forceinline__ float dot4(float4 a, float4 b) {
    return a.x * b.x + a.y * b.y + a.z * b.z + a.w * b.w;
}
__device__ __forceinline__ float dot4v(f32x4 a, f32x4 b) {
    return a.x * b.x + a.y * b.y + a.z * b.z + a.w * b.w;
}

// K1: ROUND-1 VERBATIM (~28us measured-by-inference). Lessons: float4
// weight-array reg blocking -> compiler spill/remat disaster (R2/4/5/6);
// no-LDS wave-uniform global reads -> vmem latency-bound at low occupancy
// (R9, 57us). LDS broadcast + scalar strided w is the best measured.
__global__ __launch_bounds__(256) void k_precompute(
    const float* __restrict__ emb, const float* __restrict__ w_basic,
    float* __restrict__ P1, float* __restrict__ P2, int nrows)
{
    __shared__ float embs[8][128];
    int row0 = blockIdx.x * 8;
    int t = threadIdx.x;
    for (int i = t; i < 8 * 128; i += 256) {
        int r = i >> 7, d = i & 127;
        int row = row0 + r;
        embs[r][d] = (row < nrows) ? emb[row * 128 + d] : 0.0f;
    }
    __syncthreads();
    int e = t & 127, sel = t >> 7;
    const float* wrow = w_basic + e * 256 + sel * 128;
    float acc[8] = {0, 0, 0, 0, 0, 0, 0, 0};
#pragma unroll 8
    for (int d = 0; d < 128; ++d) {
        float w = wrow[d];
#pragma unroll
        for (int r = 0; r < 8; ++r) acc[r] += embs[r][d] * w;
    }
    float* dst = sel ? P2 : P1;
#pragma unroll
    for (int r = 0; r < 8; ++r) {
        int row = row0 + r;
        if (row < nrows) dst[row * 128 + e] = acc[r];
    }
}

// K2: attention + visit embedding x[bv,128]  (unchanged)
__global__ __launch_bounds__(256) void k_attention(
    const int* __restrict__ seqs, const int* __restrict__ ancestors,
    const float* __restrict__ amask, const float* __restrict__ emb,
    const float* __restrict__ P1, const float* __restrict__ P2,
    const float* __restrict__ u_w, const float* __restrict__ u_b,
    float* __restrict__ x_out)
{
    __shared__ __align__(16) float u_s[128];
    __shared__ float sc_s[144];
    __shared__ float m_s[144];
    __shared__ int   anc_s[144];
    __shared__ float attn_s[144];
    __shared__ float sum_s[24];
    __shared__ float xred[256];
    int bv = blockIdx.x;
    int t = threadIdx.x;
    if (t < 128) u_s[t] = u_w[t];
    __syncthreads();
    float ub = u_b[0];
    int g = t >> 2, l = t & 3;
    for (int p = g; p < CC * AA; p += 64) {
        int c = p / AA, a = p - c * AA;
        int sidx = bv * CC + c;
        int s_code = seqs[sidx];
        int aidx = sidx * AA + a;
        int anc = ancestors[aidx];
        float m = amask[aidx];
        const float4* p14 = (const float4*)(P1 + s_code * 128);
        const float4* p24 = (const float4*)(P2 + anc * 128);
        const float4* u4 = (const float4*)u_s;
        float partial = 0.0f;
        int e4 = l * 8;
#pragma unroll 2
        for (int j = 0; j < 8; ++j) {
            float4 av = p14[e4 + j];
            float4 bv_ = p24[e4 + j];
            float4 uv = u4[e4 + j];
            partial += fast_tanh(m * (av.x + bv_.x)) * uv.x;
            partial += fast_tanh(m * (av.y + bv_.y)) * uv.y;
            partial += fast_tanh(m * (av.z + bv_.z)) * uv.z;
            partial += fast_tanh(m * (av.w + bv_.w)) * uv.w;
        }
        partial += __shfl_xor(partial, 1);
        partial += __shfl_xor(partial, 2);
        if (l == 0) {
            sc_s[p] = partial + ub;
            m_s[p] = m;
            anc_s[p] = anc;
        }
    }
    __syncthreads();
    if (t < CC * AA) attn_s[t] = __expf(sc_s[t]) * m_s[t];
    __syncthreads();
    if (t < CC) {
        float s = 0.0f;
#pragma unroll
        for (int a = 0; a < AA; ++a) s += attn_s[t * AA + a];
        sum_s[t] = (s == 0.0f) ? -1.0f : s;
    }
    __syncthreads();
    if (t < CC * AA) attn_s[t] = attn_s[t] / sum_s[t / AA];
    __syncthreads();
    int e = t & 127, hc = t >> 7;
    float acc = 0.0f;
    for (int c = hc * 12; c < hc * 12 + 12; ++c) {
#pragma unroll
        for (int a = 0; a < AA; ++a) {
            int p = c * AA + a;
            acc += attn_s[p] * emb[anc_s[p] * 128 + e];
        }
    }
    xred[t] = acc;
    __syncthreads();
    if (t < 128) {
        x_out[bv * 128 + t] = fast_tanh(xred[t] + xred[t + 128]);
    }
}

// K3: gi[bv,o] = sum_d x[bv,d]*Wih[o,d] + bih[o]  (unchanged from R9)
__global__ __launch_bounds__(384) void k_gi(
    const float* __restrict__ x, const float* __restrict__ wih,
    const float* __restrict__ bih, float* __restrict__ gi)
{
    int row0 = blockIdx.x * 8;
    int t = threadIdx.x;
    const float4* w4 = (const float4*)(wih + t * 128);
    const float4* x4 = (const float4*)(x + row0 * 128);
    float acc[8] = {};
#pragma unroll 2
    for (int d4 = 0; d4 < 32; ++d4) {
        float4 wv = w4[d4];
#pragma unroll
        for (int r = 0; r < 8; ++r) {
            acc[r] += dot4(x4[r * 32 + d4], wv);
        }
    }
    float bb = bih[t];
#pragma unroll
    for (int r = 0; r < 8; ++r) gi[(row0 + r) * G3 + t] = acc[r] + bb;
}

#define GL4(dst, base, OFF) \
    asm volatile("global_load_dwordx4 %0, %1, off offset:" #OFF \
                 : "=v"(dst) : "v"(base))

// K4: sequential GRU. Round-10 change: TWO batch elements per block
// (512 threads, 2 waves/SIMD). k_gru was 53-59us across FIVE structures
// whose invariant is 1 wave/SIMD = zero TLP: all ds_read/shfl/trans/barrier
// latency fully exposed (~2100 of 2650 cyc/step is stall). Two lockstep GRU
// streams per SIMD let one stream's compute fill the other's stalls.
__global__ __launch_bounds__(512, 1) void k_gru(
    const float* __restrict__ gi, const float* __restrict__ whh,
    const float* __restrict__ bhh, const int* __restrict__ length,
    const float* __restrict__ out_w, const float* __restrict__ out_b,
    float* __restrict__ out)
{
    __shared__ __align__(16) float gl[2][24 * G3];   // 73,728 B
    __shared__ __align__(16) float hs[2][2][128];
    __shared__ __align__(16) float ctxs[2][128];
    int t = threadIdx.x;
    int tb = t >> 8;            // sub-batch 0/1
    int tt = t & 255;
    int b = blockIdx.x * 2 + tb;
    int o = tt >> 1, half = tt & 1;

    const f32x4* bwr = (const f32x4*)(whh + o * 128 + half * 64);
    const f32x4* bwz = (const f32x4*)(whh + (128 + o) * 128 + half * 64);
    const f32x4* bwn = (const f32x4*)(whh + (256 + o) * 128 + half * 64);

    f32x4 wr0, wr1, wr2, wr3, wr4, wr5, wr6, wr7,
          wr8, wr9, wr10, wr11, wr12, wr13, wr14, wr15;
    f32x4 wz0, wz1, wz2, wz3, wz4, wz5, wz6, wz7,
          wz8, wz9, wz10, wz11, wz12, wz13, wz14, wz15;
    f32x4 wn0, wn1, wn2, wn3, wn4, wn5, wn6, wn7,
          wn8, wn9, wn10, wn11, wn12, wn13, wn14, wn15;

    GL4(wr0,  bwr, 0);   GL4(wr1,  bwr, 16);  GL4(wr2,  bwr, 32);  GL4(wr3,  bwr, 48);
    GL4(wr4,  bwr, 64);  GL4(wr5,  bwr, 80);  GL4(wr6,  bwr, 96);  GL4(wr7,  bwr, 112);
    GL4(wr8,  bwr, 128); GL4(wr9,  bwr, 144); GL4(wr10, bwr, 160); GL4(wr11, bwr, 176);
    GL4(wr12, bwr, 192); GL4(wr13, bwr, 208); GL4(wr14, bwr, 224); GL4(wr15, bwr, 240);
    GL4(wz0,  bwz, 0);   GL4(wz1,  bwz, 16);  GL4(wz2,  bwz, 32);  GL4(wz3,  bwz, 48);
    GL4(wz4,  bwz, 64);  GL4(wz5,  bwz, 80);  GL4(wz6,  bwz, 96);  GL4(wz7,  bwz, 112);
    GL4(wz8,  bwz, 128); GL4(wz9,  bwz, 144); GL4(wz10, bwz, 160); GL4(wz11, bwz, 176);
    GL4(wz12, bwz, 192); GL4(wz13, bwz, 208); GL4(wz14, bwz, 224); GL4(wz15, bwz, 240);
    GL4(wn0,  bwn, 0);   GL4(wn1,  bwn, 16);  GL4(wn2,  bwn, 32);  GL4(wn3,  bwn, 48);
    GL4(wn4,  bwn, 64);  GL4(wn5,  bwn, 80);  GL4(wn6,  bwn, 96);  GL4(wn7,  bwn, 112);
    GL4(wn8,  bwn, 128); GL4(wn9,  bwn, 144); GL4(wn10, bwn, 160); GL4(wn11, bwn, 176);
    GL4(wn12, bwn, 192); GL4(wn13, bwn, 208); GL4(wn14, bwn, 224); GL4(wn15, bwn, 240);

    const float4* gib4 = (const float4*)(gi + b * VV * G3);
    {
        float4* dst = (float4*)gl[tb];
#pragma unroll
        for (int i = 0; i < 9; ++i) dst[tt + i * 256] = gib4[tt + i * 256];
    }

    float bhr = 0.f, bhz = 0.f, bhn = 0.f;
    if (half == 0) {
        bhr = bhh[o];
        bhz = bhh[128 + o];
        bhn = bhh[256 + o];
    }
    if (tt < 128) hs[tb][0][tt] = 0.0f;
    int len = length[b];
    float ctx = 0.0f;

    asm volatile("s_waitcnt vmcnt(0)" ::: "memory");
    __builtin_amdgcn_sched_barrier(0);
    __syncthreads();

#define STEP2(J, A, B_) do {                                          \
        f32x4 hA = h4[J]; f32x4 hB = h4[J + 1];                       \
        ar0 += dot4v(wr##A, hA);  ar1 += dot4v(wr##B_, hB);           \
        az0 += dot4v(wz##A, hA);  az1 += dot4v(wz##B_, hB);           \
        an0 += dot4v(wn##A, hA);  an1 += dot4v(wn##B_, hB);           \
    } while (0)

    int cur = 0;
    for (int v = 0; v < VV; ++v) {
        if (v == 24) {
            float4* dst = (float4*)gl[tb];
            const float4* src = gib4 + 2304;
#pragma unroll
            for (int i = 0; i < 9; ++i) dst[tt + i * 256] = src[tt + i * 256];
            __syncthreads();
        }
        int vv = (v >= 24) ? (v - 24) : v;
        float gir = 0.f, giz = 0.f, gin = 0.f;
        if (half == 0) {
            const float* g = gl[tb] + vv * G3;
            gir = g[o]; giz = g[128 + o]; gin = g[256 + o];
        }
        const f32x4* h4 = ((const f32x4*)hs[tb][cur]) + half * 16;
        float ar0 = 0.f, ar1 = 0.f, az0 = 0.f, az1 = 0.f, an0 = 0.f, an1 = 0.f;
        STEP2(0, 0, 1);   STEP2(2, 2, 3);    STEP2(4, 4, 5);    STEP2(6, 6, 7);
        STEP2(8, 8, 9);   STEP2(10, 10, 11); STEP2(12, 12, 13); STEP2(14, 14, 15);
        float ar = ar0 + ar1;
        float az = az0 + az1;
        float an = an0 + an1;
        ar += __shfl_xor(ar, 1);
        az += __shfl_xor(az, 1);
        an += __shfl_xor(an, 1);
        if (half == 0) {
            float r = fast_sigmoid(gir + ar + bhr);
            float z = fast_sigmoid(giz + az + bhz);
            float n = fast_tanh(gin + r * (an + bhn));
            float hold = hs[tb][cur][o];
            float hnew = (1.0f - z) * n + z * hold;
            hs[tb][cur ^ 1][o] = hnew;
            if (v < len) ctx += hnew;
        }
        cur ^= 1;
        __syncthreads();
    }
#undef STEP2

    if (half == 0) ctxs[tb][o] = ctx;
    __syncthreads();
    if (tt < OUTN) {
        const float4* w4 = (const float4*)(out_w + tt * 128);
        const float4* c4 = (const float4*)ctxs[tb];
        float a0 = 0.f, a1 = 0.f;
#pragma unroll 2
        for (int j = 0; j < 32; j += 2) {
            a0 += dot4(w4[j], c4[j]);
            a1 += dot4(w4[j + 1], c4[j + 1]);
        }
        out[b * OUTN + tt] = fast_sigmoid(a0 + a1 + out_b[tt]);
    }
}

extern "C" void kernel_launch(void* const* d_in, const int* in_sizes, int n_in,
                              void* d_out, int out_size, void* d_ws, size_t ws_size,
                              hipStream_t stream) {
    const int*   seqs      = (const int*)d_in[0];
    const int*   ancestors = (const int*)d_in[1];
    const int*   length    = (const int*)d_in[2];
    const float* amask     = (const float*)d_in[3];
    const float* emb       = (const float*)d_in[4];
    const float* w_basic   = (const float*)d_in[5];
    const float* u_w       = (const float*)d_in[6];
    const float* u_b       = (const float*)d_in[7];
    const float* wih       = (const float*)d_in[8];
    const float* whh       = (const float*)d_in[9];
    const float* bih       = (const float*)d_in[10];
    const float* bhh       = (const float*)d_in[11];
    const float* out_w     = (const float*)d_in[12];
    const float* out_b     = (const float*)d_in[13];
    float* out = (float*)d_out;

    float* ws = (float*)d_ws;
    float* P1 = ws;                       // [10001,128]
    float* P2 = P1 + NCODES * 128;        // [10001,128]
    float* x  = P2 + NCODES * 128;        // [1536,128]
    float* gi = x + BB * VV * 128;        // [1536,384]

    k_precompute<<<(NCODES + 7) / 8, 256, 0, stream>>>(emb, w_basic, P1, P2, NCODES);
    k_attention<<<BB * VV, 256, 0, stream>>>(seqs, ancestors, amask, emb, P1, P2, u_w, u_b, x);
    k_gi<<<(BB * VV) / 8, 384, 0, stream>>>(x, wih, bih, gi);
    k_gru<<<BB / 2, 512, 0, stream>>>(gi, whh, bhh, length, out_w, out_b, out);
}

// Round 11
// 135.020 us; speedup vs baseline: 1.2170x; 1.1381x over previous
//
#include <hip/hip_runtime.h>

#define BB 32
#define VV 48
#define CC 24
#define AA 6
#define NCODES 10001
#define DD 128
#define HH 128
#define OUTN 167
#define G3 384  // 3*H

typedef float f32x4 __attribute__((ext_vector_type(4)));

__device__ __forceinline__ float fast_tanh(float x) {
    return 1.0f - 2.0f / (1.0f + __expf(2.0f * x));
}
__device__ __forceinline__ float fast_sigmoid(float x) {
    return 1.0f / (1.0f + __expf(-x));
}
__device__ __forceinline__ float dot4(float4 a, float4 b) {
    return a.x * b.x + a.y * b.y + a.z * b.z + a.w * b.w;
}
__device__ __forceinline__ float dot4v(f32x4 a, f32x4 b) {
    return a.x * b.x + a.y * b.y + a.z * b.z + a.w * b.w;
}

// K1: P1/P2 FUSED per thread: both halves of W[e] multiply the SAME emb
// d-range (0..127), so one emb LDS-broadcast feeds 2 dot4s. 16-row float4
// LDS staging. Small static acc arrays only (R2/4/5/6 spill lesson).
__global__ __launch_bounds__(256) void k_precompute(
    const float* __restrict__ emb, const float* __restrict__ w_basic,
    float* __restrict__ P1, float* __restrict__ P2, int nrows)
{
    __shared__ float4 embs4[16 * 32];
    int row0 = blockIdx.x * 16;
    int t = threadIdx.x;
    for (int i = t; i < 512; i += 256) {
        int r = i >> 5;
        int row = row0 + r;
        float4 v = make_float4(0.f, 0.f, 0.f, 0.f);
        if (row < nrows) v = ((const float4*)emb)[row * 32 + (i & 31)];
        embs4[i] = v;
    }
    __syncthreads();
    int e = t & 127, grp = t >> 7;          // grp: rows 0-7 / 8-15
    const float4* w1 = (const float4*)(w_basic + e * 256);        // P1 d-slice
    const float4* w2 = (const float4*)(w_basic + e * 256 + 128);  // P2 d-slice
    float a0[8] = {}, a1[8] = {};
#pragma unroll 2
    for (int d4 = 0; d4 < 32; ++d4) {
        float4 wv1 = w1[d4];
        float4 wv2 = w2[d4];
#pragma unroll
        for (int r = 0; r < 8; ++r) {
            float4 ev = embs4[(grp * 8 + r) * 32 + d4];   // wave-uniform bcast
            a0[r] += dot4(ev, wv1);
            a1[r] += dot4(ev, wv2);
        }
    }
#pragma unroll
    for (int r = 0; r < 8; ++r) {
        int row = row0 + grp * 8 + r;
        if (row < nrows) {
            P1[row * 128 + e] = a0[r];
            P2[row * 128 + e] = a1[r];
        }
    }
}

// K2: attention + visit embedding. Round-11: mask-skip — m==0 pairs skip the
// P1/P2 loads + tanh loop (saves ~30% gather traffic), and attn==0 rows skip
// the phase-2 emb gather (uniform branch across the half-block).
__global__ __launch_bounds__(256) void k_attention(
    const int* __restrict__ seqs, const int* __restrict__ ancestors,
    const float* __restrict__ amask, const float* __restrict__ emb,
    const float* __restrict__ P1, const float* __restrict__ P2,
    const float* __restrict__ u_w, const float* __restrict__ u_b,
    float* __restrict__ x_out)
{
    __shared__ __align__(16) float u_s[128];
    __shared__ float sc_s[144];
    __shared__ float m_s[144];
    __shared__ int   anc_s[144];
    __shared__ float attn_s[144];
    __shared__ float sum_s[24];
    __shared__ float xred[256];
    int bv = blockIdx.x;
    int t = threadIdx.x;
    if (t < 128) u_s[t] = u_w[t];
    __syncthreads();
    float ub = u_b[0];
    int g = t >> 2, l = t & 3;
    for (int p = g; p < CC * AA; p += 64) {
        int c = p / AA, a = p - c * AA;
        int sidx = bv * CC + c;
        int aidx = sidx * AA + a;
        int anc = ancestors[aidx];
        float m = amask[aidx];
        if (l == 0) { m_s[p] = m; anc_s[p] = anc; }
        if (m != 0.0f) {
            int s_code = seqs[sidx];
            const float4* p14 = (const float4*)(P1 + s_code * 128);
            const float4* p24 = (const float4*)(P2 + anc * 128);
            const float4* u4 = (const float4*)u_s;
            float partial = 0.0f;
            int e4 = l * 8;
#pragma unroll 2
            for (int j = 0; j < 8; ++j) {
                float4 av = p14[e4 + j];
                float4 bv_ = p24[e4 + j];
                float4 uv = u4[e4 + j];
                partial += fast_tanh(m * (av.x + bv_.x)) * uv.x;
                partial += fast_tanh(m * (av.y + bv_.y)) * uv.y;
                partial += fast_tanh(m * (av.z + bv_.z)) * uv.z;
                partial += fast_tanh(m * (av.w + bv_.w)) * uv.w;
            }
            partial += __shfl_xor(partial, 1);
            partial += __shfl_xor(partial, 2);
            if (l == 0) sc_s[p] = partial + ub;
        } else {
            if (l == 0) sc_s[p] = 0.0f;
        }
    }
    __syncthreads();
    if (t < CC * AA) {
        float m = m_s[t];
        attn_s[t] = (m != 0.0f) ? __expf(sc_s[t]) * m : 0.0f;
    }
    __syncthreads();
    if (t < CC) {
        float s = 0.0f;
#pragma unroll
        for (int a = 0; a < AA; ++a) s += attn_s[t * AA + a];
        sum_s[t] = (s == 0.0f) ? -1.0f : s;
    }
    __syncthreads();
    if (t < CC * AA) attn_s[t] = attn_s[t] / sum_s[t / AA];
    __syncthreads();
    int e = t & 127, hc = t >> 7;
    float acc = 0.0f;
    for (int c = hc * 12; c < hc * 12 + 12; ++c) {
#pragma unroll
        for (int a = 0; a < AA; ++a) {
            int p = c * AA + a;
            float at = attn_s[p];
            if (at != 0.0f) acc += at * emb[anc_s[p] * 128 + e];
        }
    }
    xred[t] = acc;
    __syncthreads();
    if (t < 128) {
        x_out[bv * 128 + t] = fast_tanh(xred[t] + xred[t + 128]);
    }
}

// K3: gi[bv,o] = sum_d x[bv,d]*Wih[o,d] + bih[o]  (unchanged, ~3us)
__global__ __launch_bounds__(384) void k_gi(
    const float* __restrict__ x, const float* __restrict__ wih,
    const float* __restrict__ bih, float* __restrict__ gi)
{
    int row0 = blockIdx.x * 8;
    int t = threadIdx.x;
    const float4* w4 = (const float4*)(wih + t * 128);
    const float4* x4 = (const float4*)(x + row0 * 128);
    float acc[8] = {};
#pragma unroll 2
    for (int d4 = 0; d4 < 32; ++d4) {
        float4 wv = w4[d4];
#pragma unroll
        for (int r = 0; r < 8; ++r) {
            acc[r] += dot4(x4[r * 32 + d4], wv);
        }
    }
    float bb = bih[t];
#pragma unroll
    for (int r = 0; r < 8; ++r) gi[(row0 + r) * G3 + t] = acc[r] + bb;
}

#define GL4(dst, base, OFF) \
    asm volatile("global_load_dwordx4 %0, %1, off offset:" #OFF \
                 : "=v"(dst) : "v"(base))

// K4: sequential GRU. Round-11: 512 threads, SAME 32-block grid.
// R10 showed intra-SIMD wave overlap gives ~1.5x per-CU throughput but
// halving the grid negated it. Now: 2 waves/SIMD TLP without shrinking the
// grid. Thread (o = t>>2, q = t&3) owns a 32-wide K-slice of the 3 gate rows:
// 24 asm-pinned float4 (96 VGPR, R7/8-proven no-spill), 8 h-reads/thread,
// 2-shfl reduction. gi staged in LDS (R9: zero in-loop vmem).
__global__ __launch_bounds__(512, 1) void k_gru(
    const float* __restrict__ gi, const float* __restrict__ whh,
    const float* __restrict__ bhh, const int* __restrict__ length,
    const float* __restrict__ out_w, const float* __restrict__ out_b,
    float* __restrict__ out)
{
    __shared__ __align__(16) float gl[24 * G3];      // 36,864 B
    __shared__ __align__(16) float hs[2][128];
    __shared__ __align__(16) float ctxs[128];
    int b = blockIdx.x;
    int t = threadIdx.x;
    int o = t >> 2, q = t & 3;

    const f32x4* bwr = (const f32x4*)(whh + o * 128 + q * 32);
    const f32x4* bwz = (const f32x4*)(whh + (128 + o) * 128 + q * 32);
    const f32x4* bwn = (const f32x4*)(whh + (256 + o) * 128 + q * 32);

    f32x4 wr0, wr1, wr2, wr3, wr4, wr5, wr6, wr7;
    f32x4 wz0, wz1, wz2, wz3, wz4, wz5, wz6, wz7;
    f32x4 wn0, wn1, wn2, wn3, wn4, wn5, wn6, wn7;

    GL4(wr0, bwr, 0);  GL4(wr1, bwr, 16); GL4(wr2, bwr, 32); GL4(wr3, bwr, 48);
    GL4(wr4, bwr, 64); GL4(wr5, bwr, 80); GL4(wr6, bwr, 96); GL4(wr7, bwr, 112);
    GL4(wz0, bwz, 0);  GL4(wz1, bwz, 16); GL4(wz2, bwz, 32); GL4(wz3, bwz, 48);
    GL4(wz4, bwz, 64); GL4(wz5, bwz, 80); GL4(wz6, bwz, 96); GL4(wz7, bwz, 112);
    GL4(wn0, bwn, 0);  GL4(wn1, bwn, 16); GL4(wn2, bwn, 32); GL4(wn3, bwn, 48);
    GL4(wn4, bwn, 64); GL4(wn5, bwn, 80); GL4(wn6, bwn, 96); GL4(wn7, bwn, 112);

    const float4* gib4 = (const float4*)(gi + b * VV * G3);
    {
        float4* dst = (float4*)gl;
#pragma unroll
        for (int i = 0; i < 5; ++i) {
            int idx = t + i * 512;
            if (idx < 2304) dst[idx] = gib4[idx];
        }
    }

    float bhr = 0.f, bhz = 0.f, bhn = 0.f;
    if (q == 0) {
        bhr = bhh[o];
        bhz = bhh[128 + o];
        bhn = bhh[256 + o];
    }
    if (t < 128) hs[0][t] = 0.0f;
    int len = length[b];
    float ctx = 0.0f;

    asm volatile("s_waitcnt vmcnt(0)" ::: "memory");
    __builtin_amdgcn_sched_barrier(0);
    __syncthreads();

#define STEPJ(J) do {                                                  \
        f32x4 hv = h4[J];                                              \
        ar += dot4v(wr##J, hv);                                        \
        az += dot4v(wz##J, hv);                                        \
        an += dot4v(wn##J, hv);                                        \
    } while (0)

    int cur = 0;
    for (int v = 0; v < VV; ++v) {
        if (v == 24) {
            float4* dst = (float4*)gl;
            const float4* src = gib4 + 2304;
#pragma unroll
            for (int i = 0; i < 5; ++i) {
                int idx = t + i * 512;
                if (idx < 2304) dst[idx] = src[idx];
            }
            __syncthreads();
        }
        int vv = (v >= 24) ? (v - 24) : v;
        float gir = 0.f, giz = 0.f, gin = 0.f;
        if (q == 0) {
            const float* g = gl + vv * G3;
            gir = g[o]; giz = g[128 + o]; gin = g[256 + o];
        }
        const f32x4* h4 = ((const f32x4*)hs[cur]) + q * 8;
        float ar = 0.f, az = 0.f, an = 0.f;
        STEPJ(0); STEPJ(1); STEPJ(2); STEPJ(3);
        STEPJ(4); STEPJ(5); STEPJ(6); STEPJ(7);
        ar += __shfl_xor(ar, 1);
        az += __shfl_xor(az, 1);
        an += __shfl_xor(an, 1);
        ar += __shfl_xor(ar, 2);
        az += __shfl_xor(az, 2);
        an += __shfl_xor(an, 2);
        if (q == 0) {
            float r = fast_sigmoid(gir + ar + bhr);
            float z = fast_sigmoid(giz + az + bhz);
            float n = fast_tanh(gin + r * (an + bhn));
            float hold = hs[cur][o];
            float hnew = (1.0f - z) * n + z * hold;
            hs[cur ^ 1][o] = hnew;
            if (v < len) ctx += hnew;
        }
        cur ^= 1;
        __syncthreads();
    }
#undef STEPJ

    if (q == 0) ctxs[o] = ctx;
    __syncthreads();
    if (t < OUTN) {
        const float4* w4 = (const float4*)(out_w + t * 128);
        const float4* c4 = (const float4*)ctxs;
        float a0 = 0.f, a1 = 0.f;
#pragma unroll 2
        for (int j = 0; j < 32; j += 2) {
            a0 += dot4(w4[j], c4[j]);
            a1 += dot4(w4[j + 1], c4[j + 1]);
        }
        out[b * OUTN + t] = fast_sigmoid(a0 + a1 + out_b[t]);
    }
}

extern "C" void kernel_launch(void* const* d_in, const int* in_sizes, int n_in,
                              void* d_out, int out_size, void* d_ws, size_t ws_size,
                              hipStream_t stream) {
    const int*   seqs      = (const int*)d_in[0];
    const int*   ancestors = (const int*)d_in[1];
    const int*   length    = (const int*)d_in[2];
    const float* amask     = (const float*)d_in[3];
    const float* emb       = (const float*)d_in[4];
    const float* w_basic   = (const float*)d_in[5];
    const float* u_w       = (const float*)d_in[6];
    const float* u_b       = (const float*)d_in[7];
    const float* wih       = (const float*)d_in[8];
    const float* whh       = (const float*)d_in[9];
    const float* bih       = (const float*)d_in[10];
    const float* bhh       = (const float*)d_in[11];
    const float* out_w     = (const float*)d_in[12];
    const float* out_b     = (const float*)d_in[13];
    float* out = (float*)d_out;

    float* ws = (float*)d_ws;
    float* P1 = ws;                       // [10001,128]
    float* P2 = P1 + NCODES * 128;        // [10001,128]
    float* x  = P2 + NCODES * 128;        // [1536,128]
    float* gi = x + BB * VV * 128;        // [1536,384]

    k_precompute<<<(NCODES + 15) / 16, 256, 0, stream>>>(emb, w_basic, P1, P2, NCODES);
    k_attention<<<BB * VV, 256, 0, stream>>>(seqs, ancestors, amask, emb, P1, P2, u_w, u_b, x);
    k_gi<<<(BB * VV) / 8, 384, 0, stream>>>(x, wih, bih, gi);
    k_gru<<<BB, 512, 0, stream>>>(gi, whh, bhh, length, out_w, out_b, out);
}